// Round 9
// baseline (53.302 us; speedup 1.0000x reference)
//
#include <hip/hip_runtime.h>
#include <hip/hip_bf16.h>
#include <math.h>

#define BB 32
#define SS 256
#define DD 128
#define KK 16
#define VV 50000
#define SK (SS*KK)     // 4096
#define NROW (BB*SK)   // 131072 candidate rows
#define CAP 32         // max tracked references per vocab row (λ=2.62)

typedef __attribute__((ext_vector_type(8))) short bf16x8;
typedef __attribute__((ext_vector_type(4))) float f32x4;
typedef __attribute__((ext_vector_type(16))) float f32x16;
typedef unsigned short ushort_t;

static __device__ __forceinline__ short f2bf(float f) {
    __hip_bfloat16 h = __float2bfloat16(f);
    return *(short*)&h;
}

// byte offset of (row, d) in a [R][128] bf16 LDS tile, XOR-swizzled:
// 16B-chunk q -> q ^ (row & 15). Frag reads 2 lanes/bank = free.
static __device__ __forceinline__ int lds_off(int row, int d) {
    return row * 256 + ((d * 2) ^ ((row & 15) << 4));
}

static __device__ __forceinline__ void gload_lds16(const void* g, void* lds) {
    __builtin_amdgcn_global_load_lds(
        (const __attribute__((address_space(1))) unsigned int*)g,
        (__attribute__((address_space(3))) unsigned int*)lds, 16, 0, 0);
}

#define NLAT (BB*SS*DD)       // 1,048,576
#define NCHUNK_LAT (NLAT/8)   // 131,072

// ---------------- K2: build inverted index slot lists -----------------------
__global__ __launch_bounds__(256)
void build_kernel(const int* __restrict__ labels,
                  const int* __restrict__ samples,
                  const float* __restrict__ embed,
                  int* __restrict__ counts,    // [V] (pre-zeroed)
                  int* __restrict__ slots,     // [V*CAP]
                  ushort_t* __restrict__ wsB)  // overflow fallback target
{
    const int s  = blockIdx.x * 256 + threadIdx.x;   // slot 0..131071
    const int b  = s >> 12;
    const int gc = s & 4095;
    const int j  = gc >> 4;
    const int k  = gc & 15;
    const int v  = (k < 15)
        ? samples[(size_t)b * (SS * (KK - 1)) + j * (KK - 1) + k]
        : labels[b * SS + j];
    const int pos = atomicAdd(&counts[v], 1);
    if (pos < CAP) {
        slots[v * CAP + pos] = s;
    } else {
        // ~never happens with random indices; exactness guarantee
        const float* src = embed + (size_t)v * DD;
        ushort_t* dst = wsB + (size_t)s * DD;
        for (int e = 0; e < DD; ++e) dst[e] = (ushort_t)f2bf(src[e]);
    }
}

// ---------------- K3: stream embed rows, scatter to dense wsB; latent too ---
#define SC_BLOCKS ((VV + 31) / 32)   // 32 vocab rows/block, 8 threads/row
#define GB_L (NCHUNK_LAT/256)        // 512 latent-convert blocks

__global__ __launch_bounds__(256)
void scatter_kernel(const float* __restrict__ embed,
                    const float* __restrict__ latent,
                    const int*   __restrict__ counts,
                    const int*   __restrict__ slots,
                    ushort_t* __restrict__ wsB,     // [B,SK,D] bf16 out
                    ushort_t* __restrict__ wsLat)   // [B,S,D] bf16 out
{
    const int gb = blockIdx.x;
    if (gb < SC_BLOCKS) {
        const int t  = threadIdx.x;
        const int v  = gb * 32 + (t >> 3);
        const int lt = t & 7;            // 16 floats (64 B) per thread
        if (v < VV) {
            int c = counts[v];
            if (c > 0) {
                if (c > CAP) c = CAP;
                const float* src = embed + (size_t)v * DD + lt * 16;
                float f[16];
                #pragma unroll
                for (int cc = 0; cc < 4; ++cc)
                    *(f32x4*)(f + 4 * cc) = *(const f32x4*)(src + 4 * cc);
                short o[16];
                #pragma unroll
                for (int e = 0; e < 16; ++e) o[e] = f2bf(f[e]);
                for (int p = 0; p < c; ++p) {
                    const int s = slots[v * CAP + p];
                    ushort_t* dst = wsB + (size_t)s * DD + lt * 16;
                    *(bf16x8*)(dst)     = *(bf16x8*)(o);
                    *(bf16x8*)(dst + 8) = *(bf16x8*)(o + 8);
                }
            }
        }
    } else {
        // latent fp32 -> bf16, 8 elems/thread
        const int i = (gb - SC_BLOCKS) * 256 + threadIdx.x;
        if (i < NCHUNK_LAT) {
            const float* src = latent + (size_t)i * 8;
            float f[8];
            *(f32x4*)(f + 0) = ((const f32x4*)src)[0];
            *(f32x4*)(f + 4) = ((const f32x4*)src)[1];
            short o[8];
            #pragma unroll
            for (int e = 0; e < 8; ++e) o[e] = f2bf(f[e]);
            *(bf16x8*)(wsLat + (size_t)i * 8) = *(bf16x8*)o;
        }
    }
}

// ---------------- K4: dense GEMM + fused LSE (no gathers) -------------------
#define NT 128

__global__ __launch_bounds__(256, 2)
void gemm_kernel(const ushort_t* __restrict__ lat_bf,  // [B,S,D] bf16
                 const ushort_t* __restrict__ wsB,     // [B,SK,D] bf16
                 float* __restrict__ out)              // [B,S,S]
{
    __shared__ char ldsA[SS * 256];   // 64 KB

    const int b    = blockIdx.y;
    const int n0   = blockIdx.x * NT;
    const int tid  = threadIdx.x;
    const int wave = tid >> 6;
    const int lane = tid & 63;
    const int q    = lane & 15;
    const int sub  = lane >> 4;
    const int l31  = lane & 31;
    const int hi   = lane >> 5;

    // ---- stage all 256 latent rows (async, pre-swizzled source) ----
    #pragma unroll
    for (int t = 0; t < 16; ++t) {
        const int r0 = wave * 64 + t * 4;
        const int r  = r0 + sub;
        const ushort_t* src = lat_bf + ((size_t)(b * SS + r) * DD)
                                     + ((q ^ (r & 15)) << 3);
        gload_lds16(src, ldsA + r0 * 256);
    }

    // ---- B: dense coalesced read of this lane's half-row ----
    const int rB = wave * 32 + l31;
    const ushort_t* rowp = wsB + ((size_t)(b * SK + n0 + rB)) * DD + hi * 8;
    bf16x8 av[8];
    #pragma unroll
    for (int ks = 0; ks < 8; ++ks)
        av[ks] = *(const bf16x8*)(rowp + ks * 16);

    __syncthreads();   // drains staging vmcnt; only barrier

    const int jb = (n0 >> 4) + wave * 2;

    #pragma unroll
    for (int mt = 0; mt < 4; ++mt) {
        // ---- MFMA 32x32x16, swapped: D[row=cand][col=lat] ----
        f32x16 acc0 = {}, acc1 = {};
        #pragma unroll
        for (int ks = 0; ks < 8; ++ks) {
            const int d = ks * 16 + hi * 8;
            bf16x8 bv0 = *(const bf16x8*)(ldsA + lds_off(mt * 64 + l31, d));
            bf16x8 bv1 = *(const bf16x8*)(ldsA + lds_off(mt * 64 + 32 + l31, d));
            acc0 = __builtin_amdgcn_mfma_f32_32x32x16_bf16(av[ks], bv0, acc0, 0, 0, 0);
            acc1 = __builtin_amdgcn_mfma_f32_32x32x16_bf16(av[ks], bv1, acc1, 0, 0, 0);
        }

        // ---- fused LSE epilogue (k-group along (reg,hi) axis) ----
        #pragma unroll
        for (int f = 0; f < 2; ++f) {
            const f32x16 v = f ? acc1 : acc0;
            float pm0 = fmaxf(fmaxf(fmaxf(v[0], v[1]), fmaxf(v[2], v[3])),
                              fmaxf(fmaxf(v[4], v[5]), fmaxf(v[6], v[7])));
            float pm1 = fmaxf(fmaxf(fmaxf(v[8], v[9]), fmaxf(v[10], v[11])),
                              fmaxf(fmaxf(v[12], v[13]), fmaxf(v[14], v[15])));
            float om0 = fmaxf(pm0, __shfl_xor(pm0, 32));
            float om1 = fmaxf(pm1, __shfl_xor(pm1, 32));
            float e0 = ((__expf(v[0] - om0) + __expf(v[1] - om0))
                      + (__expf(v[2] - om0) + __expf(v[3] - om0)))
                     + ((__expf(v[4] - om0) + __expf(v[5] - om0))
                      + (__expf(v[6] - om0) + __expf(v[7] - om0)));
            float e1 = ((__expf(v[8]  - om1) + __expf(v[9]  - om1))
                      + (__expf(v[10] - om1) + __expf(v[11] - om1)))
                     + ((__expf(v[12] - om1) + __expf(v[13] - om1))
                      + (__expf(v[14] - om1) + __expf(v[15] - om1)));
            float s0 = e0 + __shfl_xor(e0, 32);
            float s1 = e1 + __shfl_xor(e1, 32);
            float pos0 = __shfl_xor(v[7], 32);  // hi=0 lanes get cand row 15
            float pos1 = v[15];                 // hi=1 lanes hold cand row 31
            const float pos = hi ? pos1 : pos0;
            const float om  = hi ? om1  : om0;
            const float s   = hi ? s1   : s0;
            const int i = mt * 64 + f * 32 + l31;
            out[((size_t)b * SS + i) * SS + (jb + hi)] = pos - om - __logf(s);
        }
    }
}

// ---------------- fallback (fp32 gather + in-kernel convert) ----------------
__global__ __launch_bounds__(256)
void neg_loss_fallback(const float* __restrict__ latent,
                       const int*   __restrict__ labels,
                       const int*   __restrict__ samples,
                       const float* __restrict__ embed,
                       float* __restrict__ out)
{
    __shared__ char ldsA[64 * 256];
    __shared__ char ldsB[64 * 256];

    const int b   = blockIdx.z;
    const int m0  = blockIdx.y * 64;
    const int n0  = blockIdx.x * 64;
    const int tid = threadIdx.x;

    {
        const int r  = tid >> 2;
        const int d0 = (tid & 3) * 32;
        const float* src = latent + ((size_t)b * SS + (m0 + r)) * DD + d0;
        float f[32];
        #pragma unroll
        for (int c = 0; c < 8; ++c)
            *(float4*)(f + 4 * c) = ((const float4*)src)[c];
        #pragma unroll
        for (int c = 0; c < 4; ++c) {
            short tmp[8];
            #pragma unroll
            for (int e = 0; e < 8; ++e) tmp[e] = f2bf(f[c * 8 + e]);
            *(bf16x8*)(ldsA + lds_off(r, d0 + c * 8)) = *(bf16x8*)tmp;
        }
    }
    {
        const int c   = tid >> 2;
        const int d0  = (tid & 3) * 32;
        const int col = n0 + c;
        const int j   = col >> 4;
        const int k   = col & 15;
        const int idx = (k < 15) ? samples[(size_t)b * (SS * (KK - 1)) + j * (KK - 1) + k]
                                 : labels[b * SS + j];
        const float* src = embed + (size_t)idx * DD + d0;
        float f[32];
        #pragma unroll
        for (int cc = 0; cc < 8; ++cc)
            *(float4*)(f + 4 * cc) = ((const float4*)src)[cc];
        #pragma unroll
        for (int cc = 0; cc < 4; ++cc) {
            short tmp[8];
            #pragma unroll
            for (int e = 0; e < 8; ++e) tmp[e] = f2bf(f[cc * 8 + e]);
            *(bf16x8*)(ldsB + lds_off(c, d0 + cc * 8)) = *(bf16x8*)tmp;
        }
    }
    __syncthreads();

    const int wave = tid >> 6;
    const int lane = tid & 63;
    const int wm = wave >> 1, wn = wave & 1;
    const int lr = lane & 15;
    const int lk = (lane >> 4) * 8;
    const int sub = lane >> 4;

    f32x4 acc[2][2] = {};
    #pragma unroll
    for (int ks = 0; ks < 4; ++ks) {
        const int d = ks * 32 + lk;
        bf16x8 a[2], bb2[2];
        #pragma unroll
        for (int mf = 0; mf < 2; ++mf)
            a[mf] = *(const bf16x8*)(ldsA + lds_off(wm * 32 + mf * 16 + lr, d));
        #pragma unroll
        for (int nf = 0; nf < 2; ++nf)
            bb2[nf] = *(const bf16x8*)(ldsB + lds_off(wn * 32 + nf * 16 + lr, d));
        #pragma unroll
        for (int mf = 0; mf < 2; ++mf)
            #pragma unroll
            for (int nf = 0; nf < 2; ++nf)
                acc[mf][nf] = __builtin_amdgcn_mfma_f32_16x16x32_bf16(
                    bb2[nf], a[mf], acc[mf][nf], 0, 0, 0);
    }

    #pragma unroll
    for (int mf = 0; mf < 2; ++mf) {
        #pragma unroll
        for (int nf = 0; nf < 2; ++nf) {
            const f32x4 v = acc[mf][nf];
            float mx = fmaxf(fmaxf(v[0], v[1]), fmaxf(v[2], v[3]));
            mx = fmaxf(mx, __shfl_xor(mx, 16));
            mx = fmaxf(mx, __shfl_xor(mx, 32));
            float e = __expf(v[0] - mx) + __expf(v[1] - mx)
                    + __expf(v[2] - mx) + __expf(v[3] - mx);
            e += __shfl_xor(e, 16);
            e += __shfl_xor(e, 32);
            float pos = __shfl(v[3], (lane & 15) | 48);
            if (sub == 0) {
                const int i  = m0 + wm * 32 + mf * 16 + (lane & 15);
                const int jj = (n0 >> 4) + wn * 2 + nf;
                out[((size_t)b * SS + i) * SS + jj] = pos - mx - __logf(e);
            }
        }
    }
}

extern "C" void kernel_launch(void* const* d_in, const int* in_sizes, int n_in,
                              void* d_out, int out_size, void* d_ws, size_t ws_size,
                              hipStream_t stream) {
    const float* latent  = (const float*)d_in[0];
    const int*   labels  = (const int*)d_in[1];
    const int*   samples = (const int*)d_in[2];
    const float* embed   = (const float*)d_in[3];
    float* out = (float*)d_out;

    // ws layout: wsLat | wsB | counts | slots
    const size_t wsLat_bytes  = (size_t)NLAT * 2;
    const size_t wsB_bytes    = (size_t)NROW * DD * 2;
    const size_t counts_bytes = (size_t)VV * 4;
    const size_t slots_bytes  = (size_t)VV * CAP * 4;
    const size_t ws_needed = wsLat_bytes + wsB_bytes + counts_bytes + slots_bytes;

    if (ws_size >= ws_needed) {
        ushort_t* wsLat = (ushort_t*)d_ws;
        ushort_t* wsB   = wsLat + NLAT;
        int* counts = (int*)((char*)d_ws + wsLat_bytes + wsB_bytes);
        int* slots  = counts + VV;

        hipMemsetAsync(counts, 0, counts_bytes, stream);
        build_kernel<<<NROW / 256, 256, 0, stream>>>(
            labels, samples, embed, counts, slots, wsB);
        scatter_kernel<<<SC_BLOCKS + GB_L, 256, 0, stream>>>(
            embed, latent, counts, slots, wsB, wsLat);
        dim3 grid(SK / NT, BB);
        gemm_kernel<<<grid, dim3(256), 0, stream>>>(wsLat, wsB, out);
    } else {
        dim3 grid(SK / 64, SS / 64, BB);
        neg_loss_fallback<<<grid, dim3(256), 0, stream>>>(
            latent, labels, samples, embed, out);
    }
}

// Round 10
// 37.308 us; speedup vs baseline: 1.4287x; 1.4287x over previous
//
#include <hip/hip_runtime.h>
#include <hip/hip_bf16.h>
#include <math.h>

#define BB 32
#define SS 256
#define DD 128
#define KK 16
#define VV 50000
#define SK (SS*KK)     // 4096

typedef __attribute__((ext_vector_type(8))) short bf16x8;
typedef __attribute__((ext_vector_type(4))) float f32x4;
typedef __attribute__((ext_vector_type(16))) float f32x16;
typedef unsigned short ushort_t;

static __device__ __forceinline__ short f2bf(float f) {
    __hip_bfloat16 h = __float2bfloat16(f);
    return *(short*)&h;
}

// byte offset of (row, d) in a [R][128] bf16 LDS tile, XOR-swizzled:
// 16B-chunk q -> q ^ (row & 15). Frag reads 2 lanes/bank = free.
static __device__ __forceinline__ int lds_off(int row, int d) {
    return row * 256 + ((d * 2) ^ ((row & 15) << 4));
}

static __device__ __forceinline__ void gload_lds16(const void* g, void* lds) {
    __builtin_amdgcn_global_load_lds(
        (const __attribute__((address_space(1))) unsigned int*)g,
        (__attribute__((address_space(3))) unsigned int*)lds, 16, 0, 0);
}

#define NLAT (BB*SS*DD)       // 1,048,576
#define NCHUNK_LAT (NLAT/8)   // 131,072

// ---------------- K1: latent fp32 -> bf16 -----------------------------------
__global__ __launch_bounds__(256)
void convert_lat_kernel(const float* __restrict__ latent,
                        ushort_t* __restrict__ ws_lat)
{
    int i = blockIdx.x * 256 + threadIdx.x;
    if (i >= NCHUNK_LAT) return;
    const float* src = latent + (size_t)i * 8;
    float f[8];
    *(f32x4*)(f + 0) = ((const f32x4*)src)[0];
    *(f32x4*)(f + 4) = ((const f32x4*)src)[1];
    short o[8];
    #pragma unroll
    for (int e = 0; e < 8; ++e) o[e] = f2bf(f[e]);
    *(bf16x8*)(ws_lat + (size_t)i * 8) = *(bf16x8*)o;
}

// ---------------- K2: main ---------------------------------------------------
// grid (32 n-tiles, 32 batches) = 1024 blocks; 4 waves.
// Schedule: issue B-gather (16 dwordx4/lane) -> issue A-stage (16 gload_lds/
// thread, all 256 latent rows, 64 KB LDS) -> ONE barrier -> ks-outer MFMA loop
// (acc[4][2], convert-in-loop) -> LSE -> LDS transpose -> coalesced stores.
#define NT 128

__global__ __launch_bounds__(256)
void neg_loss_main(const ushort_t* __restrict__ lat_bf,   // [B,S,D] bf16 (ws)
                   const int*      __restrict__ labels,   // [B,S]
                   const int*      __restrict__ samples,  // [B,S*(K-1)]
                   const float*    __restrict__ embed,    // [V,D] fp32
                   float* __restrict__ out)               // [B,S,S]
{
    __shared__ char  ldsA[SS * 256];     // 64 KB: all 256 latent rows
    __shared__ float trans[256][9];      // 9 KB: output transpose (pad 9)

    const int b    = blockIdx.y;
    const int n0   = blockIdx.x * NT;
    const int tid  = threadIdx.x;
    const int wave = tid >> 6;
    const int lane = tid & 63;
    const int q    = lane & 15;
    const int sub  = lane >> 4;
    const int l31  = lane & 31;
    const int hi   = lane >> 5;

    // ---- candidate index for this lane's B row ----
    const int rB  = wave * 32 + l31;
    const int gc  = n0 + rB;
    const int j   = gc >> 4;
    const int k   = gc & 15;
    const int idx = (k < 15)
        ? samples[(size_t)b * (SS * (KK - 1)) + j * (KK - 1) + k]
        : labels[b * SS + j];

    // ---- issue B gather FIRST (deepest latency): lane's half-row fp32 ----
    const float* rowp = embed + (size_t)idx * DD + hi * 8;
    f32x4 fb[16];
    #pragma unroll
    for (int ks = 0; ks < 8; ++ks) {
        fb[2 * ks]     = *(const f32x4*)(rowp + ks * 16);
        fb[2 * ks + 1] = *(const f32x4*)(rowp + ks * 16 + 4);
    }

    // ---- issue A stage: 256 rows x 16 chunks, pre-swizzled source ----
    #pragma unroll
    for (int t = 0; t < 16; ++t) {
        const int r0 = wave * 64 + t * 4;
        const int r  = r0 + sub;
        const ushort_t* src = lat_bf + ((size_t)(b * SS + r) * DD)
                                     + ((q ^ (r & 15)) << 3);
        gload_lds16(src, ldsA + r0 * 256);
    }

    __syncthreads();   // single drain point: A in LDS, fb in regs

    // ---- ks-outer MFMA: all 4 m-subtiles accumulate per K-step ----
    f32x16 acc[4][2] = {};
    #pragma unroll
    for (int ks = 0; ks < 8; ++ks) {
        short t8[8];
        #pragma unroll
        for (int e = 0; e < 4; ++e) t8[e]     = f2bf(fb[2 * ks][e]);
        #pragma unroll
        for (int e = 0; e < 4; ++e) t8[4 + e] = f2bf(fb[2 * ks + 1][e]);
        const bf16x8 av = *(bf16x8*)t8;
        const int d = ks * 16 + hi * 8;
        #pragma unroll
        for (int mt = 0; mt < 4; ++mt) {
            bf16x8 bv0 = *(const bf16x8*)(ldsA + lds_off(mt * 64 + l31, d));
            bf16x8 bv1 = *(const bf16x8*)(ldsA + lds_off(mt * 64 + 32 + l31, d));
            acc[mt][0] = __builtin_amdgcn_mfma_f32_32x32x16_bf16(av, bv0, acc[mt][0], 0, 0, 0);
            acc[mt][1] = __builtin_amdgcn_mfma_f32_32x32x16_bf16(av, bv1, acc[mt][1], 0, 0, 0);
        }
    }

    // ---- fused LSE epilogue -> stash results in trans LDS ----
    // D rows/lane: (reg&3)+8*(reg>>2)+4*hi; k-group0 = regs0-7, group1 = 8-15.
    const int jc = wave * 2 + hi;   // block-local j column 0..7
    #pragma unroll
    for (int mt = 0; mt < 4; ++mt) {
        #pragma unroll
        for (int f = 0; f < 2; ++f) {
            const f32x16 v = acc[mt][f];
            float pm0 = fmaxf(fmaxf(fmaxf(v[0], v[1]), fmaxf(v[2], v[3])),
                              fmaxf(fmaxf(v[4], v[5]), fmaxf(v[6], v[7])));
            float pm1 = fmaxf(fmaxf(fmaxf(v[8], v[9]), fmaxf(v[10], v[11])),
                              fmaxf(fmaxf(v[12], v[13]), fmaxf(v[14], v[15])));
            float om0 = fmaxf(pm0, __shfl_xor(pm0, 32));
            float om1 = fmaxf(pm1, __shfl_xor(pm1, 32));
            float e0 = ((__expf(v[0] - om0) + __expf(v[1] - om0))
                      + (__expf(v[2] - om0) + __expf(v[3] - om0)))
                     + ((__expf(v[4] - om0) + __expf(v[5] - om0))
                      + (__expf(v[6] - om0) + __expf(v[7] - om0)));
            float e1 = ((__expf(v[8]  - om1) + __expf(v[9]  - om1))
                      + (__expf(v[10] - om1) + __expf(v[11] - om1)))
                     + ((__expf(v[12] - om1) + __expf(v[13] - om1))
                      + (__expf(v[14] - om1) + __expf(v[15] - om1)));
            float s0 = e0 + __shfl_xor(e0, 32);
            float s1 = e1 + __shfl_xor(e1, 32);
            float pos0 = __shfl_xor(v[7], 32);  // hi=0 lanes get cand row 15
            float pos1 = v[15];                 // hi=1 lanes hold cand row 31
            const float pos = hi ? pos1 : pos0;
            const float om  = hi ? om1  : om0;
            const float s   = hi ? s1   : s0;
            const int i = mt * 64 + f * 32 + l31;
            trans[i][jc] = pos - om - __logf(s);
        }
    }

    __syncthreads();   // all results in trans

    // ---- coalesced store: thread i writes out[b][i][j0..j0+8) as 2x16B ----
    {
        const int i  = tid;
        const int j0 = blockIdx.x * 8;
        float r[8];
        #pragma unroll
        for (int c = 0; c < 8; ++c) r[c] = trans[i][c];
        float* dst = out + ((size_t)b * SS + i) * SS + j0;
        *(f32x4*)(dst)     = *(f32x4*)(r);
        *(f32x4*)(dst + 4) = *(f32x4*)(r + 4);
    }
}

// ---------------- fallback (fp32 gather + in-kernel convert) ----------------
__global__ __launch_bounds__(256)
void neg_loss_fallback(const float* __restrict__ latent,
                       const int*   __restrict__ labels,
                       const int*   __restrict__ samples,
                       const float* __restrict__ embed,
                       float* __restrict__ out)
{
    __shared__ char ldsA[64 * 256];
    __shared__ char ldsB[64 * 256];

    const int b   = blockIdx.z;
    const int m0  = blockIdx.y * 64;
    const int n0  = blockIdx.x * 64;
    const int tid = threadIdx.x;

    {
        const int r  = tid >> 2;
        const int d0 = (tid & 3) * 32;
        const float* src = latent + ((size_t)b * SS + (m0 + r)) * DD + d0;
        float f[32];
        #pragma unroll
        for (int c = 0; c < 8; ++c)
            *(float4*)(f + 4 * c) = ((const float4*)src)[c];
        #pragma unroll
        for (int c = 0; c < 4; ++c) {
            short tmp[8];
            #pragma unroll
            for (int e = 0; e < 8; ++e) tmp[e] = f2bf(f[c * 8 + e]);
            *(bf16x8*)(ldsA + lds_off(r, d0 + c * 8)) = *(bf16x8*)tmp;
        }
    }
    {
        const int c   = tid >> 2;
        const int d0  = (tid & 3) * 32;
        const int col = n0 + c;
        const int j   = col >> 4;
        const int k   = col & 15;
        const int idx = (k < 15) ? samples[(size_t)b * (SS * (KK - 1)) + j * (KK - 1) + k]
                                 : labels[b * SS + j];
        const float* src = embed + (size_t)idx * DD + d0;
        float f[32];
        #pragma unroll
        for (int cc = 0; cc < 8; ++cc)
            *(float4*)(f + 4 * cc) = ((const float4*)src)[cc];
        #pragma unroll
        for (int cc = 0; cc < 4; ++cc) {
            short tmp[8];
            #pragma unroll
            for (int e = 0; e < 8; ++e) tmp[e] = f2bf(f[cc * 8 + e]);
            *(bf16x8*)(ldsB + lds_off(c, d0 + cc * 8)) = *(bf16x8*)tmp;
        }
    }
    __syncthreads();

    const int wave = tid >> 6;
    const int lane = tid & 63;
    const int wm = wave >> 1, wn = wave & 1;
    const int lr = lane & 15;
    const int lk = (lane >> 4) * 8;
    const int sub = lane >> 4;

    f32x4 acc[2][2] = {};
    #pragma unroll
    for (int ks = 0; ks < 4; ++ks) {
        const int d = ks * 32 + lk;
        bf16x8 a[2], bb2[2];
        #pragma unroll
        for (int mf = 0; mf < 2; ++mf)
            a[mf] = *(const bf16x8*)(ldsA + lds_off(wm * 32 + mf * 16 + lr, d));
        #pragma unroll
        for (int nf = 0; nf < 2; ++nf)
            bb2[nf] = *(const bf16x8*)(ldsB + lds_off(wn * 32 + nf * 16 + lr, d));
        #pragma unroll
        for (int mf = 0; mf < 2; ++mf)
            #pragma unroll
            for (int nf = 0; nf < 2; ++nf)
                acc[mf][nf] = __builtin_amdgcn_mfma_f32_16x16x32_bf16(
                    bb2[nf], a[mf], acc[mf][nf], 0, 0, 0);
    }

    #pragma unroll
    for (int mf = 0; mf < 2; ++mf) {
        #pragma unroll
        for (int nf = 0; nf < 2; ++nf) {
            const f32x4 v = acc[mf][nf];
            float mx = fmaxf(fmaxf(v[0], v[1]), fmaxf(v[2], v[3]));
            mx = fmaxf(mx, __shfl_xor(mx, 16));
            mx = fmaxf(mx, __shfl_xor(mx, 32));
            float e = __expf(v[0] - mx) + __expf(v[1] - mx)
                    + __expf(v[2] - mx) + __expf(v[3] - mx);
            e += __shfl_xor(e, 16);
            e += __shfl_xor(e, 32);
            float pos = __shfl(v[3], (lane & 15) | 48);
            if (sub == 0) {
                const int i  = m0 + wm * 32 + mf * 16 + (lane & 15);
                const int jj = (n0 >> 4) + wn * 2 + nf;
                out[((size_t)b * SS + i) * SS + jj] = pos - mx - __logf(e);
            }
        }
    }
}

extern "C" void kernel_launch(void* const* d_in, const int* in_sizes, int n_in,
                              void* d_out, int out_size, void* d_ws, size_t ws_size,
                              hipStream_t stream) {
    const float* latent  = (const float*)d_in[0];
    const int*   labels  = (const int*)d_in[1];
    const int*   samples = (const int*)d_in[2];
    const float* embed   = (const float*)d_in[3];
    float* out = (float*)d_out;

    const size_t ws_needed = (size_t)NLAT * 2;
    if (ws_size >= ws_needed) {
        ushort_t* ws_lat = (ushort_t*)d_ws;
        convert_lat_kernel<<<(NCHUNK_LAT + 255) / 256, 256, 0, stream>>>(
            latent, ws_lat);
        dim3 grid(SK / NT, BB);
        neg_loss_main<<<grid, dim3(256), 0, stream>>>(
            ws_lat, labels, samples, embed, out);
    } else {
        dim3 grid(SK / 64, SS / 64, BB);
        neg_loss_fallback<<<grid, dim3(256), 0, stream>>>(
            latent, labels, samples, embed, out);
    }
}

// Round 11
// 32.547 us; speedup vs baseline: 1.6377x; 1.1463x over previous
//
#include <hip/hip_runtime.h>
#include <hip/hip_bf16.h>
#include <math.h>

#define BB 32
#define SS 256
#define DD 128
#define KK 16
#define VV 50000
#define SK (SS*KK)     // 4096
#define LOG2E 1.44269504f
#define LN2   0.69314718f

typedef __attribute__((ext_vector_type(8))) short bf16x8;
typedef __attribute__((ext_vector_type(4))) float f32x4;
typedef __attribute__((ext_vector_type(16))) float f32x16;
typedef unsigned short ushort_t;

static __device__ __forceinline__ short f2bf(float f) {
    __hip_bfloat16 h = __float2bfloat16(f);
    return *(short*)&h;
}

static __device__ __forceinline__ float fast_exp2(float x) {
    float r; asm("v_exp_f32 %0, %1" : "=v"(r) : "v"(x)); return r;
}
static __device__ __forceinline__ float fast_log2(float x) {
    float r; asm("v_log_f32 %0, %1" : "=v"(r) : "v"(x)); return r;
}

// byte offset of (row, d) in the [256][128] bf16 LDS tile, XOR-swizzled:
// 16B-chunk q -> q ^ (row & 15). MFMA frag reads measured conflict-free (R10).
static __device__ __forceinline__ int lds_off(int row, int d) {
    return row * 256 + ((d * 2) ^ ((row & 15) << 4));
}

__global__ __launch_bounds__(256, 2)
void neg_loss_persist(const float* __restrict__ latent,   // [B,S,D] fp32
                      const int*   __restrict__ labels,   // [B,S]
                      const int*   __restrict__ samples,  // [B,S*(K-1)]
                      const float* __restrict__ embed,    // [V,D] fp32
                      float* __restrict__ out)            // [B,S,S]
{
    __shared__ char  ldsA[SS * 256];   // 64 KB: all 256 latent rows (x log2e)
    __shared__ float trans[256][9];    // 9 KB: output transpose staging

    const int p     = blockIdx.x;      // 0..511: b = p>>4, n-pair = p&15
    const int b     = p >> 4;
    const int npair = p & 15;
    const int tid   = threadIdx.x;
    const int wave  = tid >> 6;
    const int lane  = tid & 63;
    const int l31   = lane & 31;
    const int hi    = lane >> 5;

    // ---- candidate indices for both tiles (this lane's B rows) ----
    const int rB  = wave * 32 + l31;
    const int gc0 = (npair * 2) * 128 + rB;
    const int gc1 = gc0 + 128;
    const int j0i = gc0 >> 4, k0i = gc0 & 15;
    const int j1i = gc1 >> 4, k1i = gc1 & 15;
    const int idx0 = (k0i < 15)
        ? samples[(size_t)b * (SS * (KK - 1)) + j0i * (KK - 1) + k0i]
        : labels[b * SS + j0i];
    const int idx1 = (k1i < 15)
        ? samples[(size_t)b * (SS * (KK - 1)) + j1i * (KK - 1) + k1i]
        : labels[b * SS + j1i];

    // ---- issue tile0 gather FIRST (latency hides under A-staging) ----
    f32x4 fbA[16];
    {
        const float* rowp = embed + (size_t)idx0 * DD + hi * 8;
        #pragma unroll
        for (int ks = 0; ks < 8; ++ks) {
            fbA[2 * ks]     = *(const f32x4*)(rowp + ks * 16);
            fbA[2 * ks + 1] = *(const f32x4*)(rowp + ks * 16 + 4);
        }
    }

    // ---- stage A: 256 latent rows fp32 -> bf16 * LOG2E, swizzled ds_write --
    // 4 threads/row, 4 passes of 64 rows. Write pattern analyzed conflict-free
    // (uniform 8 words/bank per instr).
    #pragma unroll
    for (int pr = 0; pr < 4; ++pr) {
        const int r  = pr * 64 + (tid >> 2);
        const int d0 = (tid & 3) * 32;
        const float* src = latent + ((size_t)b * SS + r) * DD + d0;
        f32x4 f[8];
        #pragma unroll
        for (int c = 0; c < 8; ++c) f[c] = *(const f32x4*)(src + 4 * c);
        short o[32];
        #pragma unroll
        for (int c = 0; c < 8; ++c)
            #pragma unroll
            for (int e = 0; e < 4; ++e)
                o[4 * c + e] = f2bf(f[c][e] * LOG2E);
        #pragma unroll
        for (int c = 0; c < 4; ++c)
            *(bf16x8*)(ldsA + lds_off(r, d0 + 8 * c)) = *(bf16x8*)(o + 8 * c);
    }

    __syncthreads();   // A resident; fbA arrived

    // ---- issue tile1 gather now: latency hides under tile0 compute ----
    f32x4 fbB[16];
    {
        const float* rowp = embed + (size_t)idx1 * DD + hi * 8;
        #pragma unroll
        for (int ks = 0; ks < 8; ++ks) {
            fbB[2 * ks]     = *(const f32x4*)(rowp + ks * 16);
            fbB[2 * ks + 1] = *(const f32x4*)(rowp + ks * 16 + 4);
        }
    }

    // ================= two tiles, identical bodies =================
    #pragma unroll
    for (int t = 0; t < 2; ++t) {
        const int tile_n = npair * 2 + t;
        const int jc     = wave * 2 + hi;   // block-local j column 0..7

        // convert this tile's gathered half-row to bf16 fragments
        bf16x8 av[8];
        #pragma unroll
        for (int ks = 0; ks < 8; ++ks) {
            const f32x4 lo = t ? fbB[2 * ks]     : fbA[2 * ks];
            const f32x4 hi4 = t ? fbB[2 * ks + 1] : fbA[2 * ks + 1];
            short t8[8];
            #pragma unroll
            for (int e = 0; e < 4; ++e) t8[e]     = f2bf(lo[e]);
            #pragma unroll
            for (int e = 0; e < 4; ++e) t8[4 + e] = f2bf(hi4[e]);
            av[ks] = *(bf16x8*)t8;
        }

        // ---- MFMA 32x32x16, swapped: D[row=cand][col=lat(scaled)] ----
        f32x16 acc[4][2] = {};
        #pragma unroll
        for (int ks = 0; ks < 8; ++ks) {
            const int d = ks * 16 + hi * 8;
            #pragma unroll
            for (int mt = 0; mt < 4; ++mt) {
                bf16x8 bv0 = *(const bf16x8*)(ldsA + lds_off(mt * 64 + l31, d));
                bf16x8 bv1 = *(const bf16x8*)(ldsA + lds_off(mt * 64 + 32 + l31, d));
                acc[mt][0] = __builtin_amdgcn_mfma_f32_32x32x16_bf16(av[ks], bv0, acc[mt][0], 0, 0, 0);
                acc[mt][1] = __builtin_amdgcn_mfma_f32_32x32x16_bf16(av[ks], bv1, acc[mt][1], 0, 0, 0);
            }
        }

        // ---- fused LSE (base-2 domain) -> trans ----
        // D rows/lane: (reg&3)+8*(reg>>2)+4*hi; group0 = regs0-7, group1 = 8-15.
        #pragma unroll
        for (int mt = 0; mt < 4; ++mt) {
            #pragma unroll
            for (int f = 0; f < 2; ++f) {
                const f32x16 v = acc[mt][f];
                float pm0 = fmaxf(fmaxf(fmaxf(v[0], v[1]), fmaxf(v[2], v[3])),
                                  fmaxf(fmaxf(v[4], v[5]), fmaxf(v[6], v[7])));
                float pm1 = fmaxf(fmaxf(fmaxf(v[8], v[9]), fmaxf(v[10], v[11])),
                                  fmaxf(fmaxf(v[12], v[13]), fmaxf(v[14], v[15])));
                float om0 = fmaxf(pm0, __shfl_xor(pm0, 32));
                float om1 = fmaxf(pm1, __shfl_xor(pm1, 32));
                float e0 = ((fast_exp2(v[0] - om0) + fast_exp2(v[1] - om0))
                          + (fast_exp2(v[2] - om0) + fast_exp2(v[3] - om0)))
                         + ((fast_exp2(v[4] - om0) + fast_exp2(v[5] - om0))
                          + (fast_exp2(v[6] - om0) + fast_exp2(v[7] - om0)));
                float e1 = ((fast_exp2(v[8]  - om1) + fast_exp2(v[9]  - om1))
                          + (fast_exp2(v[10] - om1) + fast_exp2(v[11] - om1)))
                         + ((fast_exp2(v[12] - om1) + fast_exp2(v[13] - om1))
                          + (fast_exp2(v[14] - om1) + fast_exp2(v[15] - om1)));
                float s0 = e0 + __shfl_xor(e0, 32);
                float s1 = e1 + __shfl_xor(e1, 32);
                float pos0 = __shfl_xor(v[7], 32);  // hi=0 lanes get cand row 15
                float pos1 = v[15];                 // hi=1 lanes hold cand row 31
                const float pos = hi ? pos1 : pos0;
                const float om  = hi ? om1  : om0;
                const float s   = hi ? s1   : s0;
                const int i = mt * 64 + f * 32 + l31;
                trans[i][jc] = (pos - om - fast_log2(s)) * LN2;
            }
        }

        __syncthreads();   // trans complete

        // ---- store: thread i writes out[b][i][tile_n*8 .. +8) as 2x16B ----
        {
            const int i = tid;
            float r[8];
            #pragma unroll
            for (int c = 0; c < 8; ++c) r[c] = trans[i][c];
            float* dst = out + ((size_t)b * SS + i) * SS + tile_n * 8;
            *(f32x4*)(dst)     = *(f32x4*)(r);
            *(f32x4*)(dst + 4) = *(f32x4*)(r + 4);
        }

        if (t == 0) __syncthreads();   // protect trans before tile1 overwrites
    }
}

extern "C" void kernel_launch(void* const* d_in, const int* in_sizes, int n_in,
                              void* d_out, int out_size, void* d_ws, size_t ws_size,
                              hipStream_t stream) {
    const float* latent  = (const float*)d_in[0];
    const int*   labels  = (const int*)d_in[1];
    const int*   samples = (const int*)d_in[2];
    const float* embed   = (const float*)d_in[3];
    float* out = (float*)d_out;

    neg_loss_persist<<<dim3(512), dim3(256), 0, stream>>>(
        latent, labels, samples, embed, out);
}